// Round 8
// baseline (765.254 us; speedup 1.0000x reference)
//
#include <hip/hip_runtime.h>
#include <math.h>

// B=32, C_IN=3, H=W=128, MID=64
// All three 3x3 convs on matrix cores via fp16 2-way split (hi + lo*2^11):
// 3 MFMA products per tile => ~fp32 precision. 9 shifted K=64 GEMMs per conv,
// input staged in LDS as split-fp16. pos stride = 140 B (35 dwords, odd mod 32)
// -> B-fragment ds_read_b128 is ~2-way banked (was 144 B = 8-way, 10.1M confl).
// Launch chain compressed: k_prep (zero + 3x weight transform) and last-block
// ticket fusion of bn0-into-xstats and finalize-into-stats.

typedef _Float16 half8_t __attribute__((ext_vector_type(8)));
typedef float f32x4 __attribute__((ext_vector_type(4)));

__device__ inline unsigned short f16bits(_Float16 h) {
  union { _Float16 h; unsigned short u; } cv; cv.h = h; return cv.u;
}

// ------- prep: zero stats/counters + W[co][ci][kh][kw] -> A-frag split-fp16 -------
// Wp fp16 idx = (((s*2+p)*8 + (ci>>3))*64 + co)*8 + (ci&7); p=0 hi, p=1 lo*2^11
__global__ __launch_bounds__(256) void k_prep(const float* __restrict__ w1,
                                              const float* __restrict__ w2,
                                              const float* __restrict__ w3,
                                              _Float16* __restrict__ Wp,
                                              float* __restrict__ zb) {
  int blk = blockIdx.x;
  if (blk >= 432) {           // zero st(384) + xst(16) + cnt(4)
    int i = (blk - 432) * 256 + threadIdx.x;
    if (i < 404) zb[i] = 0.f;
    return;
  }
  int layer = blk / 144;
  const float* w = (layer == 0) ? w1 : (layer == 1) ? w2 : w3;
  _Float16* W = Wp + (size_t)layer * 73728;
  int i = (blk % 144) * 256 + threadIdx.x;   // 0..36863
  int s = i >> 12, rem = i & 4095;
  int ci = rem >> 6, co = rem & 63;
  float wv = w[(co * 64 + ci) * 9 + s];
  _Float16 hi = (_Float16)wv;
  _Float16 lo = (_Float16)((wv - (float)hi) * 2048.0f);
  int g = ci >> 3, e = ci & 7;
  W[(((size_t)(s * 2 + 0) * 8 + g) * 64 + co) * 8 + e] = hi;
  W[(((size_t)(s * 2 + 1) * 8 + g) * 64 + co) * 8 + e] = lo;
}

// ------- x channel stats + fused analytic BN0 (last-block ticket) -------
__global__ __launch_bounds__(256) void k_xstats(const float* __restrict__ x,
                                                float* __restrict__ xst,
                                                unsigned* __restrict__ cnt,
                                                const float* __restrict__ w0,
                                                const float* __restrict__ gamma,
                                                const float* __restrict__ beta,
                                                float* __restrict__ sb0) {
  int g0 = blockIdx.x * 256 + threadIdx.x;
  float a[9] = {0,0,0,0,0,0,0,0,0};
  for (int g = g0; g < 524288; g += 1024 * 256) {
    int b = g >> 14, p = g & 16383;
    const float* xb = x + (size_t)b * 49152 + p;
    float x0 = xb[0], x1 = xb[16384], x2 = xb[32768];
    a[0] += x0; a[1] += x1; a[2] += x2;
    a[3] += x0 * x0; a[4] += x0 * x1; a[5] += x0 * x2;
    a[6] += x1 * x1; a[7] += x1 * x2; a[8] += x2 * x2;
  }
  __shared__ float red[256];
  for (int k = 0; k < 9; ++k) {
    red[threadIdx.x] = a[k];
    __syncthreads();
    for (int s = 128; s > 0; s >>= 1) {
      if (threadIdx.x < s) red[threadIdx.x] += red[threadIdx.x + s];
      __syncthreads();
    }
    if (threadIdx.x == 0) atomicAdd(&xst[k], red[0]);
    __syncthreads();
  }
  __shared__ int lastf;
  if (threadIdx.x == 0) {
    __threadfence();
    lastf = (atomicAdd(cnt, 1u) == (unsigned)(gridDim.x - 1));
  }
  __syncthreads();
  if (!lastf) return;
  __shared__ float xs[9];
  if (threadIdx.x < 9) xs[threadIdx.x] = atomicAdd(&xst[threadIdx.x], 0.f);
  __syncthreads();
  int c = threadIdx.x;
  if (c < 64) {
    const float invN = 1.f / 524288.f;
    float mu0 = xs[0]*invN, mu1 = xs[1]*invN, mu2 = xs[2]*invN;
    float M00 = xs[3]*invN, M01 = xs[4]*invN, M02 = xs[5]*invN;
    float M11 = xs[6]*invN, M12 = xs[7]*invN, M22 = xs[8]*invN;
    float wa = w0[c*3], wb = w0[c*3+1], wc = w0[c*3+2];
    float m  = wa*mu0 + wb*mu1 + wc*mu2;
    float e2 = wa*wa*M00 + wb*wb*M11 + wc*wc*M22
             + 2.f*(wa*wb*M01 + wa*wc*M02 + wb*wc*M12);
    float var = e2 - m*m;
    float sc = gamma[c] / sqrtf(var + 1e-5f);
    sb0[2*c] = sc;
    sb0[2*c+1] = beta[c] - m*sc;
  }
}

// ------- layer1 on MFMA: bnrelu(w0.x) staged split-fp16 -> 9-shift GEMM -> pool
__global__ __launch_bounds__(256) void k_conv1_mfma(
    const float* __restrict__ x, const float* __restrict__ w0,
    const _Float16* __restrict__ Wp, const float* __restrict__ sb0,
    float* __restrict__ out) {
  __shared__ __align__(16) unsigned char smem[50160];
  float* x_lds = (float*)(smem + 46200);   // 330 pos * 140 B = 46200

  int bid = blockIdx.x;
  int cb = bid & 1, pr = (bid >> 1) % 62, b = (bid >> 1) / 62;
  int CB = cb * 62;
  int t = threadIdx.x;
  int lane = t & 63, wv = t >> 6;
  int cwv = wv * 16;
  int l15 = lane & 15, l4 = lane >> 4;

  for (int i = t; i < 990; i += 256) {
    int ch = i / 330, pos = i - ch * 330;
    int ir = pos / 66, ic = pos - ir * 66;
    x_lds[ch * 330 + pos] =
        x[((size_t)(b * 3 + ch) << 14) + (2 * pr + ir) * 128 + CB + ic];
  }

  f32x4 acc1[3][4], acc2[3][4];
  #pragma unroll
  for (int r = 0; r < 3; ++r)
    #pragma unroll
    for (int ct = 0; ct < 4; ++ct) {
      acc1[r][ct] = (f32x4)0.f;
      acc2[r][ct] = (f32x4)0.f;
    }

  int pair = t & 15;
  int posb = t >> 4;
  int LB = l15 * 140 + l4 * 16;

  for (int q = 0; q < 2; ++q) {
    int ci0 = q * 32 + 2 * pair, ci1 = ci0 + 1;
    float w00 = w0[ci0*3], w01 = w0[ci0*3+1], w02 = w0[ci0*3+2];
    float w10 = w0[ci1*3], w11 = w0[ci1*3+1], w12 = w0[ci1*3+2];
    float sc0 = sb0[2*ci0], bi0 = sb0[2*ci0+1];
    float sc1 = sb0[2*ci1], bi1 = sb0[2*ci1+1];
    __syncthreads();
    for (int pos = posb; pos < 330; pos += 16) {
      float x0 = x_lds[pos], x1 = x_lds[330 + pos], x2 = x_lds[660 + pos];
      float v0 = fmaxf(fmaf(fmaf(x2, w02, fmaf(x1, w01, x0 * w00)), sc0, bi0), 0.f);
      float v1 = fmaxf(fmaf(fmaf(x2, w12, fmaf(x1, w11, x0 * w10)), sc1, bi1), 0.f);
      _Float16 h0 = (_Float16)v0, h1 = (_Float16)v1;
      _Float16 g0 = (_Float16)((v0 - (float)h0) * 2048.f);
      _Float16 g1 = (_Float16)((v1 - (float)h1) * 2048.f);
      unsigned uh = f16bits(h0) | ((unsigned)f16bits(h1) << 16);
      unsigned ul = f16bits(g0) | ((unsigned)f16bits(g1) << 16);
      int base = pos * 140 + pair * 4;
      *(unsigned*)(smem + base) = uh;
      *(unsigned*)(smem + base + 64) = ul;
    }
    __syncthreads();

    #pragma unroll
    for (int s = 0; s < 9; ++s) {
      const int kh = s / 3, kw = s % 3;
      half8_t Ah[4], Al[4];
      #pragma unroll
      for (int ct = 0; ct < 4; ++ct) {
        Ah[ct] = *(const half8_t*)(Wp + ((size_t)((s*2+0)*8 + q*4 + l4) * 64 + ct*16 + l15) * 8);
        Al[ct] = *(const half8_t*)(Wp + ((size_t)((s*2+1)*8 + q*4 + l4) * 64 + ct*16 + l15) * 8);
      }
      #pragma unroll
      for (int r = 0; r < 3; ++r) {
        int rowoff = ((r + kh) * 66 + cwv + kw) * 140 + LB;
        half8_t Bh = *(const half8_t*)(smem + rowoff);
        half8_t Bl = *(const half8_t*)(smem + rowoff + 64);
        #pragma unroll
        for (int ct = 0; ct < 4; ++ct) {
          acc1[r][ct] = __builtin_amdgcn_mfma_f32_16x16x32_f16(Ah[ct], Bh, acc1[r][ct], 0, 0, 0);
          acc2[r][ct] = __builtin_amdgcn_mfma_f32_16x16x32_f16(Ah[ct], Bl, acc2[r][ct], 0, 0, 0);
          acc2[r][ct] = __builtin_amdgcn_mfma_f32_16x16x32_f16(Al[ct], Bh, acc2[r][ct], 0, 0, 0);
        }
      }
    }
  }

  __syncthreads();
  float* ctile = (float*)smem;   // [64 co][3 r][65] = 49920 B
  #pragma unroll
  for (int r = 0; r < 3; ++r)
    #pragma unroll
    for (int ct = 0; ct < 4; ++ct)
      #pragma unroll
      for (int e = 0; e < 4; ++e) {
        int co = ct * 16 + l4 * 4 + e;
        ctile[(co * 3 + r) * 65 + cwv + l15] =
            acc1[r][ct][e] + acc2[r][ct][e] * (1.f / 2048.f);
      }
  __syncthreads();
  for (int i = t; i < 64 * 31; i += 256) {
    int co = i / 31, pcl = i - co * 31;
    float m = -INFINITY;
    #pragma unroll
    for (int dr = 0; dr < 3; ++dr)
      #pragma unroll
      for (int dc = 0; dc < 3; ++dc)
        m = fmaxf(m, ctile[(co * 3 + dr) * 65 + 2 * pcl + dc]);
    out[((size_t)(b * 64 + co) * 62 + pr) * 62 + cb * 31 + pcl] = m;
  }
}

// ------- layers 2/3 on MFMA: bnrelu(in) staged split-fp16 -> 9-shift GEMM -> pool
template<int IN, int POOLW, int NH>
__global__ __launch_bounds__(256) void k_convpool_mfma(
    const float* __restrict__ in, const _Float16* __restrict__ Wp,
    const float* __restrict__ sb, float* __restrict__ out) {
  __shared__ __align__(16) unsigned char smem[25344];  // stage 23800 / ctile 25344

  int bid = blockIdx.x;
  int h  = (NH == 2) ? (bid & 1) : 0;
  int pw = (NH == 2) ? (bid >> 1) : bid;
  int pr = pw % POOLW;
  int b  = pw / POOLW;
  int CB = h * 30;
  int t = threadIdx.x;
  int lane = t & 63, wv = t >> 6;
  int l15 = lane & 15, l4 = lane >> 4;
  int wc = wv & 1, wo = wv >> 1;

  f32x4 acc1[3][2], acc2[3][2];
  #pragma unroll
  for (int r = 0; r < 3; ++r)
    #pragma unroll
    for (int c = 0; c < 2; ++c) { acc1[r][c] = (f32x4)0.f; acc2[r][c] = (f32x4)0.f; }

  for (int q = 0; q < 2; ++q) {
    __syncthreads();
    for (int li = t; li < 5440; li += 256) {
      int ci = li / 170, pos = li - ci * 170;
      int ir = pos / 34, ic = pos - ir * 34;
      int gci = q * 32 + ci;
      int gc = CB + ic;
      float v = 0.f;
      if (gc < IN)
        v = fmaxf(fmaf(in[((size_t)(b * 64 + gci) * IN + 2 * pr + ir) * IN + gc],
                       sb[2 * gci], sb[2 * gci + 1]), 0.f);
      _Float16 hi = (_Float16)v;
      _Float16 lo = (_Float16)((v - (float)hi) * 2048.f);
      int base = pos * 140 + ci * 2;
      *(_Float16*)(smem + base) = hi;
      *(_Float16*)(smem + base + 64) = lo;
    }
    __syncthreads();
    #pragma unroll
    for (int s = 0; s < 9; ++s) {
      const int kh = s / 3, kw = s % 3;
      half8_t Ah[2], Al[2];
      #pragma unroll
      for (int cti = 0; cti < 2; ++cti) {
        int co = (wo * 2 + cti) * 16 + l15;
        Ah[cti] = *(const half8_t*)(Wp + ((size_t)((s*2+0)*8 + q*4 + l4) * 64 + co) * 8);
        Al[cti] = *(const half8_t*)(Wp + ((size_t)((s*2+1)*8 + q*4 + l4) * 64 + co) * 8);
      }
      #pragma unroll
      for (int r = 0; r < 3; ++r) {
        int rowoff = ((r + kh) * 34 + wc * 16 + l15 + kw) * 140 + l4 * 16;
        half8_t Bh = *(const half8_t*)(smem + rowoff);
        half8_t Bl = *(const half8_t*)(smem + rowoff + 64);
        #pragma unroll
        for (int cti = 0; cti < 2; ++cti) {
          acc1[r][cti] = __builtin_amdgcn_mfma_f32_16x16x32_f16(Ah[cti], Bh, acc1[r][cti], 0, 0, 0);
          acc2[r][cti] = __builtin_amdgcn_mfma_f32_16x16x32_f16(Ah[cti], Bl, acc2[r][cti], 0, 0, 0);
          acc2[r][cti] = __builtin_amdgcn_mfma_f32_16x16x32_f16(Al[cti], Bh, acc2[r][cti], 0, 0, 0);
        }
      }
    }
  }

  __syncthreads();
  float* ctile = (float*)smem;   // [64 co][3 r][33]
  #pragma unroll
  for (int r = 0; r < 3; ++r)
    #pragma unroll
    for (int cti = 0; cti < 2; ++cti)
      #pragma unroll
      for (int e = 0; e < 4; ++e) {
        int co = (wo * 2 + cti) * 16 + l4 * 4 + e;
        ctile[(co * 3 + r) * 33 + wc * 16 + l15] =
            acc1[r][cti][e] + acc2[r][cti][e] * (1.f / 2048.f);
      }
  __syncthreads();
  constexpr int NPC = (NH == 1) ? POOLW : 15;
  int pc0 = h * 15;
  for (int i = t; i < 64 * NPC; i += 256) {
    int co = i / NPC, pcl = i - co * NPC;
    int pc = pc0 + pcl;
    if (pc >= POOLW) continue;
    float m = -INFINITY;
    #pragma unroll
    for (int dr = 0; dr < 3; ++dr)
      #pragma unroll
      for (int dc = 0; dc < 3; ++dc)
        m = fmaxf(m, ctile[(co * 3 + dr) * 33 + 2 * pcl + dc]);
    out[((size_t)(b * 64 + co) * POOLW + pr) * POOLW + pc] = m;
  }
}

// ------- per-channel sum/sumsq + fused finalize (last-block ticket) -------
__global__ __launch_bounds__(256) void k_stats(const float* __restrict__ h,
                                               float* __restrict__ st, int S,
                                               unsigned* __restrict__ cnt,
                                               const float* __restrict__ gamma,
                                               const float* __restrict__ beta,
                                               float* __restrict__ sb,
                                               int layer, float invN) {
  int c = blockIdx.x & 63, b = blockIdx.x >> 6;
  const float* base = h + (size_t)(b * 64 + c) * S;
  float s = 0.f, s2 = 0.f;
  for (int i = threadIdx.x; i < S; i += 256) {
    float v = base[i]; s += v; s2 += v * v;
  }
  __shared__ float r1[256], r2[256];
  r1[threadIdx.x] = s; r2[threadIdx.x] = s2;
  __syncthreads();
  for (int str = 128; str > 0; str >>= 1) {
    if (threadIdx.x < str) {
      r1[threadIdx.x] += r1[threadIdx.x + str];
      r2[threadIdx.x] += r2[threadIdx.x + str];
    }
    __syncthreads();
  }
  __shared__ int lastf;
  if (threadIdx.x == 0) {
    atomicAdd(&st[2 * c],     r1[0]);
    atomicAdd(&st[2 * c + 1], r2[0]);
    __threadfence();
    lastf = (atomicAdd(cnt, 1u) == (unsigned)(gridDim.x - 1));
  }
  __syncthreads();
  if (!lastf) return;
  int t = threadIdx.x;
  if (t < 64) {
    float s1 = atomicAdd(&st[2 * t], 0.f);
    float sq = atomicAdd(&st[2 * t + 1], 0.f);
    float m   = s1 * invN;
    float var = sq * invN - m * m;
    float sc  = gamma[layer * 64 + t] / sqrtf(var + 1e-5f);
    sb[2 * t]     = sc;
    sb[2 * t + 1] = beta[layer * 64 + t] - m * sc;
  }
}

// ---------------- theta = bnrelu(h3_flat) @ W_reg.T + b_reg ----------------
__global__ __launch_bounds__(256) void k_theta(const float* __restrict__ h3,
                                               const float* __restrict__ sb3,
                                               const float* __restrict__ Wreg,
                                               const float* __restrict__ breg,
                                               float* __restrict__ theta_raw) {
  int b = blockIdx.x, tid = threadIdx.x;
  float acc[6] = {0.f, 0.f, 0.f, 0.f, 0.f, 0.f};
  const float* hb = h3 + (size_t)b * 10816;
  for (int i = tid; i < 10816; i += 256) {
    int c = i / 169;
    float f = fmaxf(fmaf(hb[i], sb3[2 * c], sb3[2 * c + 1]), 0.f);
    #pragma unroll
    for (int j = 0; j < 6; ++j) acc[j] += f * Wreg[j * 10816 + i];
  }
  __shared__ float red[6][256];
  #pragma unroll
  for (int j = 0; j < 6; ++j) red[j][tid] = acc[j];
  __syncthreads();
  for (int s = 128; s > 0; s >>= 1) {
    if (tid < s) {
      #pragma unroll
      for (int j = 0; j < 6; ++j) red[j][tid] += red[j][tid + s];
    }
    __syncthreads();
  }
  if (tid < 6) theta_raw[b * 6 + tid] = red[tid][0] + breg[tid];
}

// ---------------- sequential spectral normalization scan ----------------
__global__ void k_spectral(const float* __restrict__ theta_raw,
                           const float* __restrict__ u0v,
                           const float* __restrict__ v0v,
                           float* __restrict__ theta) {
  if (threadIdx.x != 0 || blockIdx.x != 0) return;
  float ua = u0v[0], ub = u0v[1];
  float va = v0v[0], vb = v0v[1], vc = v0v[2];
  for (int n = 0; n < 32; ++n) {
    float W[6];
    #pragma unroll
    for (int k = 0; k < 6; ++k) W[k] = theta_raw[n * 6 + k];
    #pragma unroll
    for (int it = 0; it < 4; ++it) {
      float t0 = W[0]*ua + W[3]*ub;
      float t1 = W[1]*ua + W[4]*ub;
      float t2 = W[2]*ua + W[5]*ub;
      float nv = fmaxf(sqrtf(t0*t0 + t1*t1 + t2*t2), 1e-12f);
      va = t0/nv; vb = t1/nv; vc = t2/nv;
      float s0 = W[0]*va + W[1]*vb + W[2]*vc;
      float s1 = W[3]*va + W[4]*vb + W[5]*vc;
      float nu = fmaxf(sqrtf(s0*s0 + s1*s1), 1e-12f);
      ua = s0/nu; ub = s1/nu;
    }
    float s0 = W[0]*va + W[1]*vb + W[2]*vc;
    float s1 = W[3]*va + W[4]*vb + W[5]*vc;
    float sigma = ua*s0 + ub*s1;
    #pragma unroll
    for (int k = 0; k < 6; ++k) theta[n * 6 + k] = W[k] / sigma;
  }
}

// ---------------- affine grid + reflection bilinear sample ----------------
__global__ __launch_bounds__(256) void k_sample(const float* __restrict__ x,
                                                const float* __restrict__ theta,
                                                float* __restrict__ out) {
  int idx = blockIdx.x * 256 + threadIdx.x;
  int b = idx >> 14, p = idx & 16383;
  int hh = p >> 7, ww = p & 127;
  const float* th = theta + b * 6;
  float xs = (2*ww + 1) * (1.f/128.f) - 1.f;
  float ys = (2*hh + 1) * (1.f/128.f) - 1.f;
  float gx = th[0]*xs + th[1]*ys + th[2];
  float gy = th[3]*xs + th[4]*ys + th[5];
  float ix = ((gx + 1.f) * 128.f - 1.f) * 0.5f;
  float iy = ((gy + 1.f) * 128.f - 1.f) * 0.5f;

  float r;
  r  = fmodf(fabsf(ix + 0.5f), 256.f);
  ix = ((r > 128.f) ? 256.f - r : r) - 0.5f;
  ix = fminf(fmaxf(ix, 0.f), 127.f);
  r  = fmodf(fabsf(iy + 0.5f), 256.f);
  iy = ((r > 128.f) ? 256.f - r : r) - 0.5f;
  iy = fminf(fmaxf(iy, 0.f), 127.f);

  float x0f = floorf(ix), y0f = floorf(iy);
  float wx = ix - x0f, wy = iy - y0f;
  int x0 = (int)x0f; x0 = min(max(x0, 0), 127); int x1 = min(x0 + 1, 127);
  int y0 = (int)y0f; y0 = min(max(y0, 0), 127); int y1 = min(y0 + 1, 127);
  float w00 = (1.f-wx)*(1.f-wy), w10 = wx*(1.f-wy);
  float w01 = (1.f-wx)*wy,       w11 = wx*wy;

  #pragma unroll
  for (int ch = 0; ch < 3; ++ch) {
    const float* xb = x + ((size_t)(b*3 + ch)) * 16384;
    float v = xb[y0*128 + x0]*w00 + xb[y0*128 + x1]*w10
            + xb[y1*128 + x0]*w01 + xb[y1*128 + x1]*w11;
    out[((size_t)(b*3 + ch)) * 16384 + p] = v;
  }
}

extern "C" void kernel_launch(void* const* d_in, const int* in_sizes, int n_in,
                              void* d_out, int out_size, void* d_ws, size_t ws_size,
                              hipStream_t stream) {
  const float* x     = (const float*)d_in[0];
  const float* w0    = (const float*)d_in[1];
  const float* w1    = (const float*)d_in[2];
  const float* w2    = (const float*)d_in[3];
  const float* w3    = (const float*)d_in[4];
  const float* gamma = (const float*)d_in[5];
  const float* beta  = (const float*)d_in[6];
  const float* Wreg  = (const float*)d_in[7];
  const float* breg  = (const float*)d_in[8];
  const float* u0v   = (const float*)d_in[9];
  const float* v0v   = (const float*)d_in[10];
  float* out = (float*)d_out;

  float* ws   = (float*)d_ws;
  float* h1   = ws;                    // 7,872,512
  float* h2   = h1 + 7872512;          // 1,722,368
  float* h3   = h2 + 1722368;          //   346,112
  float* st   = h3 + 346112;           // 384  (3 layers x 64 x 2)
  float* xst  = st + 384;              // 16
  unsigned* cnt = (unsigned*)(xst + 16);   // 4 counters
  float* sb0  = xst + 20;              // 128
  float* sbL  = sb0 + 128;             // 384
  float* traw = sbL + 384;             // 192
  float* tfin = traw + 192;            // 192
  _Float16* Wp = (_Float16*)(tfin + 192);  // 3 x 73728 halfs

  k_prep<<<434, 256, 0, stream>>>(w1, w2, w3, Wp, st);   // zero st..cnt + W transforms
  k_xstats<<<1024, 256, 0, stream>>>(x, xst, cnt + 0, w0, gamma, beta, sb0);

  k_conv1_mfma<<<32 * 62 * 2, 256, 0, stream>>>(x, w0, Wp, sb0, h1);
  k_stats<<<2048, 256, 0, stream>>>(h1, st, 3844, cnt + 1, gamma, beta, sbL, 1, 1.f / 123008.f);

  k_convpool_mfma<62, 29, 2><<<32 * 29 * 2, 256, 0, stream>>>(h1, Wp + 73728, sbL, h2);
  k_stats<<<2048, 256, 0, stream>>>(h2, st + 128, 841, cnt + 2, gamma, beta, sbL + 128, 2, 1.f / 26912.f);

  k_convpool_mfma<29, 13, 1><<<32 * 13, 256, 0, stream>>>(h2, Wp + 147456, sbL + 128, h3);
  k_stats<<<2048, 256, 0, stream>>>(h3, st + 256, 169, cnt + 3, gamma, beta, sbL + 256, 3, 1.f / 5408.f);

  k_theta<<<32, 256, 0, stream>>>(h3, sbL + 256, Wreg, breg, traw);
  k_spectral<<<1, 64, 0, stream>>>(traw, u0v, v0v, tfin);
  k_sample<<<2048, 256, 0, stream>>>(x, tfin, out);
}

// Round 9
// 666.139 us; speedup vs baseline: 1.1488x; 1.1488x over previous
//
#include <hip/hip_runtime.h>
#include <math.h>

// B=32, C_IN=3, H=W=128, MID=64
// All three 3x3 convs on matrix cores via fp16 2-way split (hi + lo*2^11):
// 3 MFMA products per tile => ~fp32 precision. 9 shifted K=64 GEMMs per conv,
// input staged in LDS as split-fp16, pos stride 144 B = [32ci hi|32ci lo|pad16].
// 144 B keeps every half8_t LDS read 16B-aligned (ds_read_b128); round-8's
// 140 B "bank fix" broke alignment -> split reads, -34% (reverted).
// Launch chain compressed: k_prep (zero + 3x weight transform), last-block
// ticket fusion of bn0-into-xstats and finalize-into-stats.

typedef _Float16 half8_t __attribute__((ext_vector_type(8)));
typedef float f32x4 __attribute__((ext_vector_type(4)));

__device__ inline unsigned short f16bits(_Float16 h) {
  union { _Float16 h; unsigned short u; } cv; cv.h = h; return cv.u;
}

// ------- prep: zero stats/counters + W[co][ci][kh][kw] -> A-frag split-fp16 -------
// Wp fp16 idx = (((s*2+p)*8 + (ci>>3))*64 + co)*8 + (ci&7); p=0 hi, p=1 lo*2^11
__global__ __launch_bounds__(256) void k_prep(const float* __restrict__ w1,
                                              const float* __restrict__ w2,
                                              const float* __restrict__ w3,
                                              _Float16* __restrict__ Wp,
                                              float* __restrict__ zb) {
  int blk = blockIdx.x;
  if (blk >= 432) {           // zero st(384) + xst(16) + cnt(4)
    int i = (blk - 432) * 256 + threadIdx.x;
    if (i < 404) zb[i] = 0.f;
    return;
  }
  int layer = blk / 144;
  const float* w = (layer == 0) ? w1 : (layer == 1) ? w2 : w3;
  _Float16* W = Wp + (size_t)layer * 73728;
  int i = (blk % 144) * 256 + threadIdx.x;   // 0..36863
  int s = i >> 12, rem = i & 4095;
  int ci = rem >> 6, co = rem & 63;
  float wv = w[(co * 64 + ci) * 9 + s];
  _Float16 hi = (_Float16)wv;
  _Float16 lo = (_Float16)((wv - (float)hi) * 2048.0f);
  int g = ci >> 3, e = ci & 7;
  W[(((size_t)(s * 2 + 0) * 8 + g) * 64 + co) * 8 + e] = hi;
  W[(((size_t)(s * 2 + 1) * 8 + g) * 64 + co) * 8 + e] = lo;
}

// ------- x channel stats + fused analytic BN0 (last-block ticket) -------
__global__ __launch_bounds__(256) void k_xstats(const float* __restrict__ x,
                                                float* __restrict__ xst,
                                                unsigned* __restrict__ cnt,
                                                const float* __restrict__ w0,
                                                const float* __restrict__ gamma,
                                                const float* __restrict__ beta,
                                                float* __restrict__ sb0) {
  int g0 = blockIdx.x * 256 + threadIdx.x;
  float a[9] = {0,0,0,0,0,0,0,0,0};
  for (int g = g0; g < 524288; g += 1024 * 256) {
    int b = g >> 14, p = g & 16383;
    const float* xb = x + (size_t)b * 49152 + p;
    float x0 = xb[0], x1 = xb[16384], x2 = xb[32768];
    a[0] += x0; a[1] += x1; a[2] += x2;
    a[3] += x0 * x0; a[4] += x0 * x1; a[5] += x0 * x2;
    a[6] += x1 * x1; a[7] += x1 * x2; a[8] += x2 * x2;
  }
  __shared__ float red[256];
  for (int k = 0; k < 9; ++k) {
    red[threadIdx.x] = a[k];
    __syncthreads();
    for (int s = 128; s > 0; s >>= 1) {
      if (threadIdx.x < s) red[threadIdx.x] += red[threadIdx.x + s];
      __syncthreads();
    }
    if (threadIdx.x == 0) atomicAdd(&xst[k], red[0]);
    __syncthreads();
  }
  __shared__ int lastf;
  if (threadIdx.x == 0) {
    __threadfence();
    lastf = (atomicAdd(cnt, 1u) == (unsigned)(gridDim.x - 1));
  }
  __syncthreads();
  if (!lastf) return;
  __shared__ float xs[9];
  if (threadIdx.x < 9) xs[threadIdx.x] = atomicAdd(&xst[threadIdx.x], 0.f);
  __syncthreads();
  int c = threadIdx.x;
  if (c < 64) {
    const float invN = 1.f / 524288.f;
    float mu0 = xs[0]*invN, mu1 = xs[1]*invN, mu2 = xs[2]*invN;
    float M00 = xs[3]*invN, M01 = xs[4]*invN, M02 = xs[5]*invN;
    float M11 = xs[6]*invN, M12 = xs[7]*invN, M22 = xs[8]*invN;
    float wa = w0[c*3], wb = w0[c*3+1], wc = w0[c*3+2];
    float m  = wa*mu0 + wb*mu1 + wc*mu2;
    float e2 = wa*wa*M00 + wb*wb*M11 + wc*wc*M22
             + 2.f*(wa*wb*M01 + wa*wc*M02 + wb*wc*M12);
    float var = e2 - m*m;
    float sc = gamma[c] / sqrtf(var + 1e-5f);
    sb0[2*c] = sc;
    sb0[2*c+1] = beta[c] - m*sc;
  }
}

// ------- layer1 on MFMA: bnrelu(w0.x) staged split-fp16 -> 9-shift GEMM -> pool
__global__ __launch_bounds__(256) void k_conv1_mfma(
    const float* __restrict__ x, const float* __restrict__ w0,
    const _Float16* __restrict__ Wp, const float* __restrict__ sb0,
    float* __restrict__ out) {
  __shared__ __align__(16) unsigned char smem[51488];
  float* x_lds = (float*)(smem + 47520);

  int bid = blockIdx.x;
  int cb = bid & 1, pr = (bid >> 1) % 62, b = (bid >> 1) / 62;
  int CB = cb * 62;
  int t = threadIdx.x;
  int lane = t & 63, wv = t >> 6;
  int cwv = wv * 16;
  int l15 = lane & 15, l4 = lane >> 4;

  for (int i = t; i < 990; i += 256) {
    int ch = i / 330, pos = i - ch * 330;
    int ir = pos / 66, ic = pos - ir * 66;
    x_lds[ch * 330 + pos] =
        x[((size_t)(b * 3 + ch) << 14) + (2 * pr + ir) * 128 + CB + ic];
  }

  f32x4 acc1[3][4], acc2[3][4];
  #pragma unroll
  for (int r = 0; r < 3; ++r)
    #pragma unroll
    for (int ct = 0; ct < 4; ++ct) {
      acc1[r][ct] = (f32x4)0.f;
      acc2[r][ct] = (f32x4)0.f;
    }

  int pair = t & 15;
  int posb = t >> 4;
  int LB = l15 * 144 + l4 * 16;

  for (int q = 0; q < 2; ++q) {
    int ci0 = q * 32 + 2 * pair, ci1 = ci0 + 1;
    float w00 = w0[ci0*3], w01 = w0[ci0*3+1], w02 = w0[ci0*3+2];
    float w10 = w0[ci1*3], w11 = w0[ci1*3+1], w12 = w0[ci1*3+2];
    float sc0 = sb0[2*ci0], bi0 = sb0[2*ci0+1];
    float sc1 = sb0[2*ci1], bi1 = sb0[2*ci1+1];
    __syncthreads();
    for (int pos = posb; pos < 330; pos += 16) {
      float x0 = x_lds[pos], x1 = x_lds[330 + pos], x2 = x_lds[660 + pos];
      float v0 = fmaxf(fmaf(fmaf(x2, w02, fmaf(x1, w01, x0 * w00)), sc0, bi0), 0.f);
      float v1 = fmaxf(fmaf(fmaf(x2, w12, fmaf(x1, w11, x0 * w10)), sc1, bi1), 0.f);
      _Float16 h0 = (_Float16)v0, h1 = (_Float16)v1;
      _Float16 g0 = (_Float16)((v0 - (float)h0) * 2048.f);
      _Float16 g1 = (_Float16)((v1 - (float)h1) * 2048.f);
      unsigned uh = f16bits(h0) | ((unsigned)f16bits(h1) << 16);
      unsigned ul = f16bits(g0) | ((unsigned)f16bits(g1) << 16);
      int base = pos * 144 + pair * 4;
      *(unsigned*)(smem + base) = uh;
      *(unsigned*)(smem + base + 64) = ul;
    }
    __syncthreads();

    #pragma unroll
    for (int s = 0; s < 9; ++s) {
      const int kh = s / 3, kw = s % 3;
      half8_t Ah[4], Al[4];
      #pragma unroll
      for (int ct = 0; ct < 4; ++ct) {
        Ah[ct] = *(const half8_t*)(Wp + ((size_t)((s*2+0)*8 + q*4 + l4) * 64 + ct*16 + l15) * 8);
        Al[ct] = *(const half8_t*)(Wp + ((size_t)((s*2+1)*8 + q*4 + l4) * 64 + ct*16 + l15) * 8);
      }
      #pragma unroll
      for (int r = 0; r < 3; ++r) {
        int rowoff = ((r + kh) * 66 + cwv + kw) * 144 + LB;
        half8_t Bh = *(const half8_t*)(smem + rowoff);
        half8_t Bl = *(const half8_t*)(smem + rowoff + 64);
        #pragma unroll
        for (int ct = 0; ct < 4; ++ct) {
          acc1[r][ct] = __builtin_amdgcn_mfma_f32_16x16x32_f16(Ah[ct], Bh, acc1[r][ct], 0, 0, 0);
          acc2[r][ct] = __builtin_amdgcn_mfma_f32_16x16x32_f16(Ah[ct], Bl, acc2[r][ct], 0, 0, 0);
          acc2[r][ct] = __builtin_amdgcn_mfma_f32_16x16x32_f16(Al[ct], Bh, acc2[r][ct], 0, 0, 0);
        }
      }
    }
  }

  __syncthreads();
  float* ctile = (float*)smem;   // [64 co][3 r][65]
  #pragma unroll
  for (int r = 0; r < 3; ++r)
    #pragma unroll
    for (int ct = 0; ct < 4; ++ct)
      #pragma unroll
      for (int e = 0; e < 4; ++e) {
        int co = ct * 16 + l4 * 4 + e;
        ctile[(co * 3 + r) * 65 + cwv + l15] =
            acc1[r][ct][e] + acc2[r][ct][e] * (1.f / 2048.f);
      }
  __syncthreads();
  for (int i = t; i < 64 * 31; i += 256) {
    int co = i / 31, pcl = i - co * 31;
    float m = -INFINITY;
    #pragma unroll
    for (int dr = 0; dr < 3; ++dr)
      #pragma unroll
      for (int dc = 0; dc < 3; ++dc)
        m = fmaxf(m, ctile[(co * 3 + dr) * 65 + 2 * pcl + dc]);
    out[((size_t)(b * 64 + co) * 62 + pr) * 62 + cb * 31 + pcl] = m;
  }
}

// ------- layers 2/3 on MFMA: bnrelu(in) staged split-fp16 -> 9-shift GEMM -> pool
template<int IN, int POOLW, int NH>
__global__ __launch_bounds__(256) void k_convpool_mfma(
    const float* __restrict__ in, const _Float16* __restrict__ Wp,
    const float* __restrict__ sb, float* __restrict__ out) {
  __shared__ __align__(16) unsigned char smem[25344];  // stage 24480 / ctile 25344

  int bid = blockIdx.x;
  int h  = (NH == 2) ? (bid & 1) : 0;
  int pw = (NH == 2) ? (bid >> 1) : bid;
  int pr = pw % POOLW;
  int b  = pw / POOLW;
  int CB = h * 30;
  int t = threadIdx.x;
  int lane = t & 63, wv = t >> 6;
  int l15 = lane & 15, l4 = lane >> 4;
  int wc = wv & 1, wo = wv >> 1;

  f32x4 acc1[3][2], acc2[3][2];
  #pragma unroll
  for (int r = 0; r < 3; ++r)
    #pragma unroll
    for (int c = 0; c < 2; ++c) { acc1[r][c] = (f32x4)0.f; acc2[r][c] = (f32x4)0.f; }

  for (int q = 0; q < 2; ++q) {
    __syncthreads();
    for (int li = t; li < 5440; li += 256) {
      int ci = li / 170, pos = li - ci * 170;
      int ir = pos / 34, ic = pos - ir * 34;
      int gci = q * 32 + ci;
      int gc = CB + ic;
      float v = 0.f;
      if (gc < IN)
        v = fmaxf(fmaf(in[((size_t)(b * 64 + gci) * IN + 2 * pr + ir) * IN + gc],
                       sb[2 * gci], sb[2 * gci + 1]), 0.f);
      _Float16 hi = (_Float16)v;
      _Float16 lo = (_Float16)((v - (float)hi) * 2048.f);
      int base = pos * 144 + ci * 2;
      *(_Float16*)(smem + base) = hi;
      *(_Float16*)(smem + base + 64) = lo;
    }
    __syncthreads();
    #pragma unroll
    for (int s = 0; s < 9; ++s) {
      const int kh = s / 3, kw = s % 3;
      half8_t Ah[2], Al[2];
      #pragma unroll
      for (int cti = 0; cti < 2; ++cti) {
        int co = (wo * 2 + cti) * 16 + l15;
        Ah[cti] = *(const half8_t*)(Wp + ((size_t)((s*2+0)*8 + q*4 + l4) * 64 + co) * 8);
        Al[cti] = *(const half8_t*)(Wp + ((size_t)((s*2+1)*8 + q*4 + l4) * 64 + co) * 8);
      }
      #pragma unroll
      for (int r = 0; r < 3; ++r) {
        int rowoff = ((r + kh) * 34 + wc * 16 + l15 + kw) * 144 + l4 * 16;
        half8_t Bh = *(const half8_t*)(smem + rowoff);
        half8_t Bl = *(const half8_t*)(smem + rowoff + 64);
        #pragma unroll
        for (int cti = 0; cti < 2; ++cti) {
          acc1[r][cti] = __builtin_amdgcn_mfma_f32_16x16x32_f16(Ah[cti], Bh, acc1[r][cti], 0, 0, 0);
          acc2[r][cti] = __builtin_amdgcn_mfma_f32_16x16x32_f16(Ah[cti], Bl, acc2[r][cti], 0, 0, 0);
          acc2[r][cti] = __builtin_amdgcn_mfma_f32_16x16x32_f16(Al[cti], Bh, acc2[r][cti], 0, 0, 0);
        }
      }
    }
  }

  __syncthreads();
  float* ctile = (float*)smem;   // [64 co][3 r][33]
  #pragma unroll
  for (int r = 0; r < 3; ++r)
    #pragma unroll
    for (int cti = 0; cti < 2; ++cti)
      #pragma unroll
      for (int e = 0; e < 4; ++e) {
        int co = (wo * 2 + cti) * 16 + l4 * 4 + e;
        ctile[(co * 3 + r) * 33 + wc * 16 + l15] =
            acc1[r][cti][e] + acc2[r][cti][e] * (1.f / 2048.f);
      }
  __syncthreads();
  constexpr int NPC = (NH == 1) ? POOLW : 15;
  int pc0 = h * 15;
  for (int i = t; i < 64 * NPC; i += 256) {
    int co = i / NPC, pcl = i - co * NPC;
    int pc = pc0 + pcl;
    if (pc >= POOLW) continue;
    float m = -INFINITY;
    #pragma unroll
    for (int dr = 0; dr < 3; ++dr)
      #pragma unroll
      for (int dc = 0; dc < 3; ++dc)
        m = fmaxf(m, ctile[(co * 3 + dr) * 33 + 2 * pcl + dc]);
    out[((size_t)(b * 64 + co) * POOLW + pr) * POOLW + pc] = m;
  }
}

// ------- per-channel sum/sumsq + fused finalize (last-block ticket) -------
__global__ __launch_bounds__(256) void k_stats(const float* __restrict__ h,
                                               float* __restrict__ st, int S,
                                               unsigned* __restrict__ cnt,
                                               const float* __restrict__ gamma,
                                               const float* __restrict__ beta,
                                               float* __restrict__ sb,
                                               int layer, float invN) {
  int c = blockIdx.x & 63, b = blockIdx.x >> 6;
  const float* base = h + (size_t)(b * 64 + c) * S;
  float s = 0.f, s2 = 0.f;
  for (int i = threadIdx.x; i < S; i += 256) {
    float v = base[i]; s += v; s2 += v * v;
  }
  __shared__ float r1[256], r2[256];
  r1[threadIdx.x] = s; r2[threadIdx.x] = s2;
  __syncthreads();
  for (int str = 128; str > 0; str >>= 1) {
    if (threadIdx.x < str) {
      r1[threadIdx.x] += r1[threadIdx.x + str];
      r2[threadIdx.x] += r2[threadIdx.x + str];
    }
    __syncthreads();
  }
  __shared__ int lastf;
  if (threadIdx.x == 0) {
    atomicAdd(&st[2 * c],     r1[0]);
    atomicAdd(&st[2 * c + 1], r2[0]);
    __threadfence();
    lastf = (atomicAdd(cnt, 1u) == (unsigned)(gridDim.x - 1));
  }
  __syncthreads();
  if (!lastf) return;
  int t = threadIdx.x;
  if (t < 64) {
    float s1 = atomicAdd(&st[2 * t], 0.f);
    float sq = atomicAdd(&st[2 * t + 1], 0.f);
    float m   = s1 * invN;
    float var = sq * invN - m * m;
    float sc  = gamma[layer * 64 + t] / sqrtf(var + 1e-5f);
    sb[2 * t]     = sc;
    sb[2 * t + 1] = beta[layer * 64 + t] - m * sc;
  }
}

// ---------------- theta = bnrelu(h3_flat) @ W_reg.T + b_reg ----------------
__global__ __launch_bounds__(256) void k_theta(const float* __restrict__ h3,
                                               const float* __restrict__ sb3,
                                               const float* __restrict__ Wreg,
                                               const float* __restrict__ breg,
                                               float* __restrict__ theta_raw) {
  int b = blockIdx.x, tid = threadIdx.x;
  float acc[6] = {0.f, 0.f, 0.f, 0.f, 0.f, 0.f};
  const float* hb = h3 + (size_t)b * 10816;
  for (int i = tid; i < 10816; i += 256) {
    int c = i / 169;
    float f = fmaxf(fmaf(hb[i], sb3[2 * c], sb3[2 * c + 1]), 0.f);
    #pragma unroll
    for (int j = 0; j < 6; ++j) acc[j] += f * Wreg[j * 10816 + i];
  }
  __shared__ float red[6][256];
  #pragma unroll
  for (int j = 0; j < 6; ++j) red[j][tid] = acc[j];
  __syncthreads();
  for (int s = 128; s > 0; s >>= 1) {
    if (tid < s) {
      #pragma unroll
      for (int j = 0; j < 6; ++j) red[j][tid] += red[j][tid + s];
    }
    __syncthreads();
  }
  if (tid < 6) theta_raw[b * 6 + tid] = red[tid][0] + breg[tid];
}

// ---------------- sequential spectral normalization scan ----------------
__global__ void k_spectral(const float* __restrict__ theta_raw,
                           const float* __restrict__ u0v,
                           const float* __restrict__ v0v,
                           float* __restrict__ theta) {
  if (threadIdx.x != 0 || blockIdx.x != 0) return;
  float ua = u0v[0], ub = u0v[1];
  float va = v0v[0], vb = v0v[1], vc = v0v[2];
  for (int n = 0; n < 32; ++n) {
    float W[6];
    #pragma unroll
    for (int k = 0; k < 6; ++k) W[k] = theta_raw[n * 6 + k];
    #pragma unroll
    for (int it = 0; it < 4; ++it) {
      float t0 = W[0]*ua + W[3]*ub;
      float t1 = W[1]*ua + W[4]*ub;
      float t2 = W[2]*ua + W[5]*ub;
      float nv = fmaxf(sqrtf(t0*t0 + t1*t1 + t2*t2), 1e-12f);
      va = t0/nv; vb = t1/nv; vc = t2/nv;
      float s0 = W[0]*va + W[1]*vb + W[2]*vc;
      float s1 = W[3]*va + W[4]*vb + W[5]*vc;
      float nu = fmaxf(sqrtf(s0*s0 + s1*s1), 1e-12f);
      ua = s0/nu; ub = s1/nu;
    }
    float s0 = W[0]*va + W[1]*vb + W[2]*vc;
    float s1 = W[3]*va + W[4]*vb + W[5]*vc;
    float sigma = ua*s0 + ub*s1;
    #pragma unroll
    for (int k = 0; k < 6; ++k) theta[n * 6 + k] = W[k] / sigma;
  }
}

// ---------------- affine grid + reflection bilinear sample ----------------
__global__ __launch_bounds__(256) void k_sample(const float* __restrict__ x,
                                                const float* __restrict__ theta,
                                                float* __restrict__ out) {
  int idx = blockIdx.x * 256 + threadIdx.x;
  int b = idx >> 14, p = idx & 16383;
  int hh = p >> 7, ww = p & 127;
  const float* th = theta + b * 6;
  float xs = (2*ww + 1) * (1.f/128.f) - 1.f;
  float ys = (2*hh + 1) * (1.f/128.f) - 1.f;
  float gx = th[0]*xs + th[1]*ys + th[2];
  float gy = th[3]*xs + th[4]*ys + th[5];
  float ix = ((gx + 1.f) * 128.f - 1.f) * 0.5f;
  float iy = ((gy + 1.f) * 128.f - 1.f) * 0.5f;

  float r;
  r  = fmodf(fabsf(ix + 0.5f), 256.f);
  ix = ((r > 128.f) ? 256.f - r : r) - 0.5f;
  ix = fminf(fmaxf(ix, 0.f), 127.f);
  r  = fmodf(fabsf(iy + 0.5f), 256.f);
  iy = ((r > 128.f) ? 256.f - r : r) - 0.5f;
  iy = fminf(fmaxf(iy, 0.f), 127.f);

  float x0f = floorf(ix), y0f = floorf(iy);
  float wx = ix - x0f, wy = iy - y0f;
  int x0 = (int)x0f; x0 = min(max(x0, 0), 127); int x1 = min(x0 + 1, 127);
  int y0 = (int)y0f; y0 = min(max(y0, 0), 127); int y1 = min(y0 + 1, 127);
  float w00 = (1.f-wx)*(1.f-wy), w10 = wx*(1.f-wy);
  float w01 = (1.f-wx)*wy,       w11 = wx*wy;

  #pragma unroll
  for (int ch = 0; ch < 3; ++ch) {
    const float* xb = x + ((size_t)(b*3 + ch)) * 16384;
    float v = xb[y0*128 + x0]*w00 + xb[y0*128 + x1]*w10
            + xb[y1*128 + x0]*w01 + xb[y1*128 + x1]*w11;
    out[((size_t)(b*3 + ch)) * 16384 + p] = v;
  }
}

extern "C" void kernel_launch(void* const* d_in, const int* in_sizes, int n_in,
                              void* d_out, int out_size, void* d_ws, size_t ws_size,
                              hipStream_t stream) {
  const float* x     = (const float*)d_in[0];
  const float* w0    = (const float*)d_in[1];
  const float* w1    = (const float*)d_in[2];
  const float* w2    = (const float*)d_in[3];
  const float* w3    = (const float*)d_in[4];
  const float* gamma = (const float*)d_in[5];
  const float* beta  = (const float*)d_in[6];
  const float* Wreg  = (const float*)d_in[7];
  const float* breg  = (const float*)d_in[8];
  const float* u0v   = (const float*)d_in[9];
  const float* v0v   = (const float*)d_in[10];
  float* out = (float*)d_out;

  float* ws   = (float*)d_ws;
  float* h1   = ws;                    // 7,872,512
  float* h2   = h1 + 7872512;          // 1,722,368
  float* h3   = h2 + 1722368;          //   346,112
  float* st   = h3 + 346112;           // 384  (3 layers x 64 x 2)
  float* xst  = st + 384;              // 16
  unsigned* cnt = (unsigned*)(xst + 16);   // 4 counters
  float* sb0  = xst + 20;              // 128
  float* sbL  = sb0 + 128;             // 384
  float* traw = sbL + 384;             // 192
  float* tfin = traw + 192;            // 192
  _Float16* Wp = (_Float16*)(tfin + 192);  // 3 x 73728 halfs

  k_prep<<<434, 256, 0, stream>>>(w1, w2, w3, Wp, st);   // zero st..cnt + W transforms
  k_xstats<<<1024, 256, 0, stream>>>(x, xst, cnt + 0, w0, gamma, beta, sb0);

  k_conv1_mfma<<<32 * 62 * 2, 256, 0, stream>>>(x, w0, Wp, sb0, h1);
  k_stats<<<2048, 256, 0, stream>>>(h1, st, 3844, cnt + 1, gamma, beta, sbL, 1, 1.f / 123008.f);

  k_convpool_mfma<62, 29, 2><<<32 * 29 * 2, 256, 0, stream>>>(h1, Wp + 73728, sbL, h2);
  k_stats<<<2048, 256, 0, stream>>>(h2, st + 128, 841, cnt + 2, gamma, beta, sbL + 128, 2, 1.f / 26912.f);

  k_convpool_mfma<29, 13, 1><<<32 * 13, 256, 0, stream>>>(h2, Wp + 147456, sbL + 128, h3);
  k_stats<<<2048, 256, 0, stream>>>(h3, st + 256, 169, cnt + 3, gamma, beta, sbL + 256, 3, 1.f / 5408.f);

  k_theta<<<32, 256, 0, stream>>>(h3, sbL + 256, Wreg, breg, traw);
  k_spectral<<<1, 64, 0, stream>>>(traw, u0v, v0v, tfin);
  k_sample<<<2048, 256, 0, stream>>>(x, tfin, out);
}

// Round 11
// 582.153 us; speedup vs baseline: 1.3145x; 1.1443x over previous
//
#include <hip/hip_runtime.h>
#include <math.h>

// B=32, C_IN=3, H=W=128, MID=64
// All three 3x3 convs on matrix cores via fp16 2-way split (hi + lo*2^11):
// 3 MFMA products per tile => ~fp32 precision. 9 shifted K=64 GEMMs per conv,
// input staged in LDS as split-fp16, pos stride 144 B = [32ci hi|32ci lo|pad16]
// (144 keeps half8 reads 16B-aligned; 140 "bank fix" regressed 34% — r8).
// r9 lesson: ticketed last-block fusion of stats/finalize cost ~78 us vs
// separate tiny kernels — reverted. conv1 staging packs via
// __builtin_amdgcn_cvt_pkrtz (returns __fp16x2 — hence fp16x2 typedef).

typedef _Float16 half8_t __attribute__((ext_vector_type(8)));
typedef __fp16 fp16x2 __attribute__((ext_vector_type(2)));
typedef float f32x4 __attribute__((ext_vector_type(4)));

// ------- prep: zero stats + W[co][ci][kh][kw] -> A-frag order, fp16 split -------
// Wp fp16 idx = (((s*2+p)*8 + (ci>>3))*64 + co)*8 + (ci&7); p=0 hi, p=1 lo*2^11
__global__ __launch_bounds__(256) void k_prep(const float* __restrict__ w1,
                                              const float* __restrict__ w2,
                                              const float* __restrict__ w3,
                                              _Float16* __restrict__ Wp,
                                              float* __restrict__ zb) {
  int blk = blockIdx.x;
  if (blk >= 432) {           // zero st(384) + xst(16)
    int i = (blk - 432) * 256 + threadIdx.x;
    if (i < 400) zb[i] = 0.f;
    return;
  }
  int layer = blk / 144;
  const float* w = (layer == 0) ? w1 : (layer == 1) ? w2 : w3;
  _Float16* W = Wp + (size_t)layer * 73728;
  int i = (blk % 144) * 256 + threadIdx.x;   // 0..36863
  int s = i >> 12, rem = i & 4095;
  int ci = rem >> 6, co = rem & 63;
  float wv = w[(co * 64 + ci) * 9 + s];
  _Float16 hi = (_Float16)wv;
  _Float16 lo = (_Float16)((wv - (float)hi) * 2048.0f);
  int g = ci >> 3, e = ci & 7;
  W[(((size_t)(s * 2 + 0) * 8 + g) * 64 + co) * 8 + e] = hi;
  W[(((size_t)(s * 2 + 1) * 8 + g) * 64 + co) * 8 + e] = lo;
}

// ---------------- x channel stats (for analytic BN0) ----------------
__global__ __launch_bounds__(256) void k_xstats(const float* __restrict__ x,
                                                float* __restrict__ xst) {
  int g0 = blockIdx.x * 256 + threadIdx.x;
  float a[9] = {0,0,0,0,0,0,0,0,0};
  for (int g = g0; g < 524288; g += 1024 * 256) {
    int b = g >> 14, p = g & 16383;
    const float* xb = x + (size_t)b * 49152 + p;
    float x0 = xb[0], x1 = xb[16384], x2 = xb[32768];
    a[0] += x0; a[1] += x1; a[2] += x2;
    a[3] += x0 * x0; a[4] += x0 * x1; a[5] += x0 * x2;
    a[6] += x1 * x1; a[7] += x1 * x2; a[8] += x2 * x2;
  }
  __shared__ float red[256];
  for (int k = 0; k < 9; ++k) {
    red[threadIdx.x] = a[k];
    __syncthreads();
    for (int s = 128; s > 0; s >>= 1) {
      if (threadIdx.x < s) red[threadIdx.x] += red[threadIdx.x + s];
      __syncthreads();
    }
    if (threadIdx.x == 0) atomicAdd(&xst[k], red[0]);
    __syncthreads();
  }
}

__global__ void k_bn0(const float* __restrict__ xst, const float* __restrict__ w0,
                      const float* __restrict__ gamma, const float* __restrict__ beta,
                      float* __restrict__ sb0) {
  int c = threadIdx.x;
  if (c >= 64) return;
  const float invN = 1.f / 524288.f;
  float mu0 = xst[0] * invN, mu1 = xst[1] * invN, mu2 = xst[2] * invN;
  float M00 = xst[3] * invN, M01 = xst[4] * invN, M02 = xst[5] * invN;
  float M11 = xst[6] * invN, M12 = xst[7] * invN, M22 = xst[8] * invN;
  float wa = w0[c * 3], wb = w0[c * 3 + 1], wc = w0[c * 3 + 2];
  float m  = wa * mu0 + wb * mu1 + wc * mu2;
  float e2 = wa * wa * M00 + wb * wb * M11 + wc * wc * M22
           + 2.f * (wa * wb * M01 + wa * wc * M02 + wb * wc * M12);
  float var = e2 - m * m;
  float sc = gamma[c] / sqrtf(var + 1e-5f);
  sb0[2 * c] = sc;
  sb0[2 * c + 1] = beta[c] - m * sc;
}

// ------- layer1 on MFMA: bnrelu(w0.x) staged split-fp16 -> 9-shift GEMM -> pool
__global__ __launch_bounds__(256) void k_conv1_mfma(
    const float* __restrict__ x, const float* __restrict__ w0,
    const _Float16* __restrict__ Wp, const float* __restrict__ sb0,
    float* __restrict__ out) {
  __shared__ __align__(16) unsigned char smem[51488];
  float* x_lds = (float*)(smem + 47520);

  int bid = blockIdx.x;
  int cb = bid & 1, pr = (bid >> 1) % 62, b = (bid >> 1) / 62;
  int CB = cb * 62;
  int t = threadIdx.x;
  int lane = t & 63, wv = t >> 6;
  int cwv = wv * 16;
  int l15 = lane & 15, l4 = lane >> 4;

  for (int i = t; i < 990; i += 256) {
    int ch = i / 330, pos = i - ch * 330;
    int ir = pos / 66, ic = pos - ir * 66;
    x_lds[ch * 330 + pos] =
        x[((size_t)(b * 3 + ch) << 14) + (2 * pr + ir) * 128 + CB + ic];
  }

  f32x4 acc1[3][4], acc2[3][4];
  #pragma unroll
  for (int r = 0; r < 3; ++r)
    #pragma unroll
    for (int ct = 0; ct < 4; ++ct) {
      acc1[r][ct] = (f32x4)0.f;
      acc2[r][ct] = (f32x4)0.f;
    }

  int pair = t & 15;
  int posb = t >> 4;
  int LB = l15 * 144 + l4 * 16;

  for (int q = 0; q < 2; ++q) {
    int ci0 = q * 32 + 2 * pair, ci1 = ci0 + 1;
    float w00 = w0[ci0*3], w01 = w0[ci0*3+1], w02 = w0[ci0*3+2];
    float w10 = w0[ci1*3], w11 = w0[ci1*3+1], w12 = w0[ci1*3+2];
    float sc0 = sb0[2*ci0], bi0 = sb0[2*ci0+1];
    float sc1 = sb0[2*ci1], bi1 = sb0[2*ci1+1];
    __syncthreads();
    for (int pos = posb; pos < 330; pos += 16) {
      float x0 = x_lds[pos], x1 = x_lds[330 + pos], x2 = x_lds[660 + pos];
      float v0 = fmaxf(fmaf(fmaf(x2, w02, fmaf(x1, w01, x0 * w00)), sc0, bi0), 0.f);
      float v1 = fmaxf(fmaf(fmaf(x2, w12, fmaf(x1, w11, x0 * w10)), sc1, bi1), 0.f);
      fp16x2 hv = __builtin_amdgcn_cvt_pkrtz(v0, v1);
      float l0 = (v0 - (float)hv[0]) * 2048.f;
      float l1 = (v1 - (float)hv[1]) * 2048.f;
      fp16x2 lv = __builtin_amdgcn_cvt_pkrtz(l0, l1);
      int base = pos * 144 + pair * 4;
      *(fp16x2*)(smem + base) = hv;
      *(fp16x2*)(smem + base + 64) = lv;
    }
    __syncthreads();

    #pragma unroll
    for (int s = 0; s < 9; ++s) {
      const int kh = s / 3, kw = s % 3;
      half8_t Ah[4], Al[4];
      #pragma unroll
      for (int ct = 0; ct < 4; ++ct) {
        Ah[ct] = *(const half8_t*)(Wp + ((size_t)((s*2+0)*8 + q*4 + l4) * 64 + ct*16 + l15) * 8);
        Al[ct] = *(const half8_t*)(Wp + ((size_t)((s*2+1)*8 + q*4 + l4) * 64 + ct*16 + l15) * 8);
      }
      #pragma unroll
      for (int r = 0; r < 3; ++r) {
        int rowoff = ((r + kh) * 66 + cwv + kw) * 144 + LB;
        half8_t Bh = *(const half8_t*)(smem + rowoff);
        half8_t Bl = *(const half8_t*)(smem + rowoff + 64);
        #pragma unroll
        for (int ct = 0; ct < 4; ++ct) {
          acc1[r][ct] = __builtin_amdgcn_mfma_f32_16x16x32_f16(Ah[ct], Bh, acc1[r][ct], 0, 0, 0);
          acc2[r][ct] = __builtin_amdgcn_mfma_f32_16x16x32_f16(Ah[ct], Bl, acc2[r][ct], 0, 0, 0);
          acc2[r][ct] = __builtin_amdgcn_mfma_f32_16x16x32_f16(Al[ct], Bh, acc2[r][ct], 0, 0, 0);
        }
      }
    }
  }

  __syncthreads();
  float* ctile = (float*)smem;   // [64 co][3 r][65]
  #pragma unroll
  for (int r = 0; r < 3; ++r)
    #pragma unroll
    for (int ct = 0; ct < 4; ++ct)
      #pragma unroll
      for (int e = 0; e < 4; ++e) {
        int co = ct * 16 + l4 * 4 + e;
        ctile[(co * 3 + r) * 65 + cwv + l15] =
            acc1[r][ct][e] + acc2[r][ct][e] * (1.f / 2048.f);
      }
  __syncthreads();
  for (int i = t; i < 64 * 31; i += 256) {
    int co = i / 31, pcl = i - co * 31;
    float m = -INFINITY;
    #pragma unroll
    for (int dr = 0; dr < 3; ++dr)
      #pragma unroll
      for (int dc = 0; dc < 3; ++dc)
        m = fmaxf(m, ctile[(co * 3 + dr) * 65 + 2 * pcl + dc]);
    out[((size_t)(b * 64 + co) * 62 + pr) * 62 + cb * 31 + pcl] = m;
  }
}

// ------- layers 2/3 on MFMA: bnrelu(in) staged split-fp16 -> 9-shift GEMM -> pool
template<int IN, int POOLW, int NH>
__global__ __launch_bounds__(256) void k_convpool_mfma(
    const float* __restrict__ in, const _Float16* __restrict__ Wp,
    const float* __restrict__ sb, float* __restrict__ out) {
  __shared__ __align__(16) unsigned char smem[25344];  // stage 24480 / ctile 25344

  int bid = blockIdx.x;
  int h  = (NH == 2) ? (bid & 1) : 0;
  int pw = (NH == 2) ? (bid >> 1) : bid;
  int pr = pw % POOLW;
  int b  = pw / POOLW;
  int CB = h * 30;
  int t = threadIdx.x;
  int lane = t & 63, wv = t >> 6;
  int l15 = lane & 15, l4 = lane >> 4;
  int wc = wv & 1, wo = wv >> 1;

  f32x4 acc1[3][2], acc2[3][2];
  #pragma unroll
  for (int r = 0; r < 3; ++r)
    #pragma unroll
    for (int c = 0; c < 2; ++c) { acc1[r][c] = (f32x4)0.f; acc2[r][c] = (f32x4)0.f; }

  for (int q = 0; q < 2; ++q) {
    __syncthreads();
    for (int li = t; li < 5440; li += 256) {
      int ci = li / 170, pos = li - ci * 170;
      int ir = pos / 34, ic = pos - ir * 34;
      int gci = q * 32 + ci;
      int gc = CB + ic;
      float v = 0.f;
      if (gc < IN)
        v = fmaxf(fmaf(in[((size_t)(b * 64 + gci) * IN + 2 * pr + ir) * IN + gc],
                       sb[2 * gci], sb[2 * gci + 1]), 0.f);
      _Float16 hi = (_Float16)v;
      _Float16 lo = (_Float16)((v - (float)hi) * 2048.f);
      int base = pos * 144 + ci * 2;
      *(_Float16*)(smem + base) = hi;
      *(_Float16*)(smem + base + 64) = lo;
    }
    __syncthreads();
    #pragma unroll
    for (int s = 0; s < 9; ++s) {
      const int kh = s / 3, kw = s % 3;
      half8_t Ah[2], Al[2];
      #pragma unroll
      for (int cti = 0; cti < 2; ++cti) {
        int co = (wo * 2 + cti) * 16 + l15;
        Ah[cti] = *(const half8_t*)(Wp + ((size_t)((s*2+0)*8 + q*4 + l4) * 64 + co) * 8);
        Al[cti] = *(const half8_t*)(Wp + ((size_t)((s*2+1)*8 + q*4 + l4) * 64 + co) * 8);
      }
      #pragma unroll
      for (int r = 0; r < 3; ++r) {
        int rowoff = ((r + kh) * 34 + wc * 16 + l15 + kw) * 144 + l4 * 16;
        half8_t Bh = *(const half8_t*)(smem + rowoff);
        half8_t Bl = *(const half8_t*)(smem + rowoff + 64);
        #pragma unroll
        for (int cti = 0; cti < 2; ++cti) {
          acc1[r][cti] = __builtin_amdgcn_mfma_f32_16x16x32_f16(Ah[cti], Bh, acc1[r][cti], 0, 0, 0);
          acc2[r][cti] = __builtin_amdgcn_mfma_f32_16x16x32_f16(Ah[cti], Bl, acc2[r][cti], 0, 0, 0);
          acc2[r][cti] = __builtin_amdgcn_mfma_f32_16x16x32_f16(Al[cti], Bh, acc2[r][cti], 0, 0, 0);
        }
      }
    }
  }

  __syncthreads();
  float* ctile = (float*)smem;   // [64 co][3 r][33]
  #pragma unroll
  for (int r = 0; r < 3; ++r)
    #pragma unroll
    for (int cti = 0; cti < 2; ++cti)
      #pragma unroll
      for (int e = 0; e < 4; ++e) {
        int co = (wo * 2 + cti) * 16 + l4 * 4 + e;
        ctile[(co * 3 + r) * 33 + wc * 16 + l15] =
            acc1[r][cti][e] + acc2[r][cti][e] * (1.f / 2048.f);
      }
  __syncthreads();
  constexpr int NPC = (NH == 1) ? POOLW : 15;
  int pc0 = h * 15;
  for (int i = t; i < 64 * NPC; i += 256) {
    int co = i / NPC, pcl = i - co * NPC;
    int pc = pc0 + pcl;
    if (pc >= POOLW) continue;
    float m = -INFINITY;
    #pragma unroll
    for (int dr = 0; dr < 3; ++dr)
      #pragma unroll
      for (int dc = 0; dc < 3; ++dc)
        m = fmaxf(m, ctile[(co * 3 + dr) * 33 + 2 * pcl + dc]);
    out[((size_t)(b * 64 + co) * POOLW + pr) * POOLW + pc] = m;
  }
}

// ---------------- per-channel sum/sumsq over (B,HW) ----------------
__global__ __launch_bounds__(256) void k_stats(const float* __restrict__ h,
                                               float* __restrict__ st, int S) {
  int c = blockIdx.x & 63, b = blockIdx.x >> 6;
  const float* base = h + (size_t)(b * 64 + c) * S;
  float s = 0.f, s2 = 0.f;
  for (int i = threadIdx.x; i < S; i += 256) {
    float v = base[i]; s += v; s2 += v * v;
  }
  __shared__ float r1[256], r2[256];
  r1[threadIdx.x] = s; r2[threadIdx.x] = s2;
  __syncthreads();
  for (int str = 128; str > 0; str >>= 1) {
    if (threadIdx.x < str) {
      r1[threadIdx.x] += r1[threadIdx.x + str];
      r2[threadIdx.x] += r2[threadIdx.x + str];
    }
    __syncthreads();
  }
  if (threadIdx.x == 0) {
    atomicAdd(&st[2 * c],     r1[0]);
    atomicAdd(&st[2 * c + 1], r2[0]);
  }
}

__global__ void k_finalize(const float* __restrict__ st,
                           const float* __restrict__ gamma,
                           const float* __restrict__ beta,
                           float* __restrict__ sb, int layer, float invN) {
  int t = threadIdx.x;
  if (t >= 64) return;
  float m   = st[2 * t] * invN;
  float var = st[2 * t + 1] * invN - m * m;
  float sc  = gamma[layer * 64 + t] / sqrtf(var + 1e-5f);
  sb[2 * t]     = sc;
  sb[2 * t + 1] = beta[layer * 64 + t] - m * sc;
}

// ---------------- theta = bnrelu(h3_flat) @ W_reg.T + b_reg ----------------
__global__ __launch_bounds__(256) void k_theta(const float* __restrict__ h3,
                                               const float* __restrict__ sb3,
                                               const float* __restrict__ Wreg,
                                               const float* __restrict__ breg,
                                               float* __restrict__ theta_raw) {
  int b = blockIdx.x, tid = threadIdx.x;
  float acc[6] = {0.f, 0.f, 0.f, 0.f, 0.f, 0.f};
  const float* hb = h3 + (size_t)b * 10816;
  for (int i = tid; i < 10816; i += 256) {
    int c = i / 169;
    float f = fmaxf(fmaf(hb[i], sb3[2 * c], sb3[2 * c + 1]), 0.f);
    #pragma unroll
    for (int j = 0; j < 6; ++j) acc[j] += f * Wreg[j * 10816 + i];
  }
  __shared__ float red[6][256];
  #pragma unroll
  for (int j = 0; j < 6; ++j) red[j][tid] = acc[j];
  __syncthreads();
  for (int s = 128; s > 0; s >>= 1) {
    if (tid < s) {
      #pragma unroll
      for (int j = 0; j < 6; ++j) red[j][tid] += red[j][tid + s];
    }
    __syncthreads();
  }
  if (tid < 6) theta_raw[b * 6 + tid] = red[tid][0] + breg[tid];
}

// ---------------- sequential spectral normalization scan ----------------
__global__ void k_spectral(const float* __restrict__ theta_raw,
                           const float* __restrict__ u0v,
                           const float* __restrict__ v0v,
                           float* __restrict__ theta) {
  if (threadIdx.x != 0 || blockIdx.x != 0) return;
  float ua = u0v[0], ub = u0v[1];
  float va = v0v[0], vb = v0v[1], vc = v0v[2];
  for (int n = 0; n < 32; ++n) {
    float W[6];
    #pragma unroll
    for (int k = 0; k < 6; ++k) W[k] = theta_raw[n * 6 + k];
    #pragma unroll
    for (int it = 0; it < 4; ++it) {
      float t0 = W[0]*ua + W[3]*ub;
      float t1 = W[1]*ua + W[4]*ub;
      float t2 = W[2]*ua + W[5]*ub;
      float nv = fmaxf(sqrtf(t0*t0 + t1*t1 + t2*t2), 1e-12f);
      va = t0/nv; vb = t1/nv; vc = t2/nv;
      float s0 = W[0]*va + W[1]*vb + W[2]*vc;
      float s1 = W[3]*va + W[4]*vb + W[5]*vc;
      float nu = fmaxf(sqrtf(s0*s0 + s1*s1), 1e-12f);
      ua = s0/nu; ub = s1/nu;
    }
    float s0 = W[0]*va + W[1]*vb + W[2]*vc;
    float s1 = W[3]*va + W[4]*vb + W[5]*vc;
    float sigma = ua*s0 + ub*s1;
    #pragma unroll
    for (int k = 0; k < 6; ++k) theta[n * 6 + k] = W[k] / sigma;
  }
}

// ---------------- affine grid + reflection bilinear sample ----------------
__global__ __launch_bounds__(256) void k_sample(const float* __restrict__ x,
                                                const float* __restrict__ theta,
                                                float* __restrict__ out) {
  int idx = blockIdx.x * 256 + threadIdx.x;
  int b = idx >> 14, p = idx & 16383;
  int hh = p >> 7, ww = p & 127;
  const float* th = theta + b * 6;
  float xs = (2*ww + 1) * (1.f/128.f) - 1.f;
  float ys = (2*hh + 1) * (1.f/128.f) - 1.f;
  float gx = th[0]*xs + th[1]*ys + th[2];
  float gy = th[3]*xs + th[4]*ys + th[5];
  float ix = ((gx + 1.f) * 128.f - 1.f) * 0.5f;
  float iy = ((gy + 1.f) * 128.f - 1.f) * 0.5f;

  float r;
  r  = fmodf(fabsf(ix + 0.5f), 256.f);
  ix = ((r > 128.f) ? 256.f - r : r) - 0.5f;
  ix = fminf(fmaxf(ix, 0.f), 127.f);
  r  = fmodf(fabsf(iy + 0.5f), 256.f);
  iy = ((r > 128.f) ? 256.f - r : r) - 0.5f;
  iy = fminf(fmaxf(iy, 0.f), 127.f);

  float x0f = floorf(ix), y0f = floorf(iy);
  float wx = ix - x0f, wy = iy - y0f;
  int x0 = (int)x0f; x0 = min(max(x0, 0), 127); int x1 = min(x0 + 1, 127);
  int y0 = (int)y0f; y0 = min(max(y0, 0), 127); int y1 = min(y0 + 1, 127);
  float w00 = (1.f-wx)*(1.f-wy), w10 = wx*(1.f-wy);
  float w01 = (1.f-wx)*wy,       w11 = wx*wy;

  #pragma unroll
  for (int ch = 0; ch < 3; ++ch) {
    const float* xb = x + ((size_t)(b*3 + ch)) * 16384;
    float v = xb[y0*128 + x0]*w00 + xb[y0*128 + x1]*w10
            + xb[y1*128 + x0]*w01 + xb[y1*128 + x1]*w11;
    out[((size_t)(b*3 + ch)) * 16384 + p] = v;
  }
}

extern "C" void kernel_launch(void* const* d_in, const int* in_sizes, int n_in,
                              void* d_out, int out_size, void* d_ws, size_t ws_size,
                              hipStream_t stream) {
  const float* x     = (const float*)d_in[0];
  const float* w0    = (const float*)d_in[1];
  const float* w1    = (const float*)d_in[2];
  const float* w2    = (const float*)d_in[3];
  const float* w3    = (const float*)d_in[4];
  const float* gamma = (const float*)d_in[5];
  const float* beta  = (const float*)d_in[6];
  const float* Wreg  = (const float*)d_in[7];
  const float* breg  = (const float*)d_in[8];
  const float* u0v   = (const float*)d_in[9];
  const float* v0v   = (const float*)d_in[10];
  float* out = (float*)d_out;

  float* ws   = (float*)d_ws;
  float* h1   = ws;                    // 7,872,512
  float* h2   = h1 + 7872512;          // 1,722,368
  float* h3   = h2 + 1722368;          //   346,112
  float* st   = h3 + 346112;           // 384  (3 layers x 64 x 2)
  float* xst  = st + 384;              // 16
  float* sb0  = xst + 16;              // 128
  float* sbL  = sb0 + 128;             // 384
  float* traw = sbL + 384;             // 192
  float* tfin = traw + 192;            // 192
  _Float16* Wp = (_Float16*)(tfin + 192);  // 3 x 73728 halfs

  k_prep<<<434, 256, 0, stream>>>(w1, w2, w3, Wp, st);   // zero st+xst + W transforms
  k_xstats<<<1024, 256, 0, stream>>>(x, xst);
  k_bn0<<<1, 64, 0, stream>>>(xst, w0, gamma, beta, sb0);

  k_conv1_mfma<<<32 * 62 * 2, 256, 0, stream>>>(x, w0, Wp, sb0, h1);
  k_stats<<<2048, 256, 0, stream>>>(h1, st, 3844);
  k_finalize<<<1, 64, 0, stream>>>(st, gamma, beta, sbL, 1, 1.f / 123008.f);

  k_convpool_mfma<62, 29, 2><<<32 * 29 * 2, 256, 0, stream>>>(h1, Wp + 73728, sbL, h2);
  k_stats<<<2048, 256, 0, stream>>>(h2, st + 128, 841);
  k_finalize<<<1, 64, 0, stream>>>(st + 128, gamma, beta, sbL + 128, 2, 1.f / 26912.f);

  k_convpool_mfma<29, 13, 1><<<32 * 13, 256, 0, stream>>>(h2, Wp + 147456, sbL + 128, h3);
  k_stats<<<2048, 256, 0, stream>>>(h3, st + 256, 169);
  k_finalize<<<1, 64, 0, stream>>>(st + 256, gamma, beta, sbL + 256, 3, 1.f / 5408.f);

  k_theta<<<32, 256, 0, stream>>>(h3, sbL + 256, Wreg, breg, traw);
  k_spectral<<<1, 64, 0, stream>>>(traw, u0v, v0v, tfin);
  k_sample<<<2048, 256, 0, stream>>>(x, tfin, out);
}